// Round 1
// baseline (4354.664 us; speedup 1.0000x reference)
//
#include <hip/hip_runtime.h>
#include <math.h>

// HSTU jagged attention: out = (silu(Q K^T)/N * mask) V   (no softmax!)
// Shapes: tq/tk (T, H*D), tv (T, H*DV), H=8, D=DV=64, N=max_seqlen=1024.
// Mask: a(x)=clamp(x-c+1, 0, M), M=L-c+1-ncand;
//       valid(n,m) = (n==m) | (a(n)>a(m)) | (a(n)==0 & a(m)<M), n<L, m<L.

#define HH   8
#define DDIM 64
#define DVV  64
#define QT   32
#define KT   32

__launch_bounds__(256, 4)
__global__ void hstu_fp32_kernel(const float* __restrict__ tq,
                                 const float* __restrict__ tk,
                                 const float* __restrict__ tv,
                                 const int* __restrict__ offsets,
                                 const int* __restrict__ pN,
                                 const int* __restrict__ ncand,
                                 const int* __restrict__ nctx,
                                 float* __restrict__ out) {
  const int b  = blockIdx.z;
  const int h  = blockIdx.y;
  const int qt = blockIdx.x;
  const int off = offsets[b];
  const int L   = offsets[b + 1] - off;
  const int n0  = qt * QT;
  if (n0 >= L) return;

  const int   N    = pN[0];
  const float invN = 1.0f / (float)N;
  const int   c    = nctx[b];
  const int   M    = L - c + 1 - ncand[b];

  __shared__ float Qs[QT][DDIM];       // 8 KB
  __shared__ float Kt[DDIM][KT + 1];   // transposed K, padded (conflict-free col reads)
  __shared__ float Vs[KT][DVV];        // 8 KB
  __shared__ float Ps[QT][KT + 1];     // padded scores

  const int tid = threadIdx.x;

  // ---- load Q tile (rows n0..n0+31), float4 coalesced ----
  for (int i = tid; i < QT * DDIM / 4; i += 256) {
    int r  = i >> 4;           // row in tile (16 float4 per row)
    int cc = (i & 15) << 2;    // float column
    int n  = n0 + r;
    float4 v4 = make_float4(0.f, 0.f, 0.f, 0.f);
    if (n < L)
      v4 = *(const float4*)(tq + (size_t)(off + n) * (HH * DDIM) + h * DDIM + cc);
    *(float4*)&Qs[r][cc] = v4;
  }

  // PV ownership: col d, 8-row strip
  const int d     = tid & 63;
  const int rbase = (tid >> 6) * 8;
  float acc[8];
#pragma unroll
  for (int i = 0; i < 8; i++) acc[i] = 0.f;

  // Key range: contextual tile needs full range; otherwise causal-ish (m <= n_max)
  const int m_hi = (n0 < c) ? L : min(n0 + QT, L);

  // Score ownership: key col sm, 4-row strip starting at g*4
  const int sm = tid & 31;
  const int g  = tid >> 5;

  for (int m0 = 0; m0 < m_hi; m0 += KT) {
    __syncthreads();  // protect LDS from previous iteration's readers

    // ---- stage K (transposed) and V tiles ----
    for (int i = tid; i < KT * DDIM / 4; i += 256) {
      int r  = i >> 4;
      int cc = (i & 15) << 2;
      int m  = m0 + r;
      float4 kv = make_float4(0.f, 0.f, 0.f, 0.f);
      float4 vv = make_float4(0.f, 0.f, 0.f, 0.f);
      if (m < L) {
        kv = *(const float4*)(tk + (size_t)(off + m) * (HH * DDIM) + h * DDIM + cc);
        vv = *(const float4*)(tv + (size_t)(off + m) * (HH * DVV) + h * DVV + cc);
      }
      Kt[cc + 0][r] = kv.x;
      Kt[cc + 1][r] = kv.y;
      Kt[cc + 2][r] = kv.z;
      Kt[cc + 3][r] = kv.w;
      *(float4*)&Vs[r][cc] = vv;
    }
    __syncthreads();

    // ---- scores: S = Q K^T for 4-row strip ----
    {
      float s[4] = {0.f, 0.f, 0.f, 0.f};
#pragma unroll
      for (int dd = 0; dd < DDIM; dd += 4) {
        float k0 = Kt[dd + 0][sm];
        float k1 = Kt[dd + 1][sm];
        float k2 = Kt[dd + 2][sm];
        float k3 = Kt[dd + 3][sm];
#pragma unroll
        for (int k = 0; k < 4; k++) {
          float4 q4 = *(const float4*)&Qs[g * 4 + k][dd];
          s[k] += q4.x * k0 + q4.y * k1 + q4.z * k2 + q4.w * k3;
        }
      }
      const int m = m0 + sm;
      const int am = min(max(m - c + 1, 0), M);
#pragma unroll
      for (int k = 0; k < 4; k++) {
        int r = g * 4 + k;
        int n = n0 + r;
        float p = 0.f;
        if (n < L && m < L) {
          int an = min(max(n - c + 1, 0), M);
          bool valid = (n == m) || (an > am) || ((an == 0) && (am < M));
          if (valid) {
            float x = s[k];  // ALPHA = 1.0
            p = (x / (1.f + __expf(-x))) * invN;
          }
        }
        Ps[r][sm] = p;
      }
    }
    __syncthreads();

    // ---- accumulate PV: acc[r] += P[r][m] * V[m][d] ----
#pragma unroll 8
    for (int m = 0; m < KT; m++) {
      float vv = Vs[m][d];
#pragma unroll
      for (int k = 0; k < 8; k++) {
        acc[k] += Ps[rbase + k][m] * vv;
      }
    }
  }

  // ---- write out ----
#pragma unroll
  for (int k = 0; k < 8; k++) {
    int n = n0 + rbase + k;
    if (n < L)
      out[(size_t)(off + n) * (HH * DVV) + h * DVV + d] = acc[k];
  }
}

extern "C" void kernel_launch(void* const* d_in, const int* in_sizes, int n_in,
                              void* d_out, int out_size, void* d_ws, size_t ws_size,
                              hipStream_t stream) {
  const float* tq      = (const float*)d_in[0];
  const float* tk      = (const float*)d_in[1];
  const float* tv      = (const float*)d_in[2];
  const int*   offsets = (const int*)d_in[3];
  const int*   pN      = (const int*)d_in[4];
  const int*   ncand   = (const int*)d_in[5];
  const int*   nctx    = (const int*)d_in[6];
  float*       out     = (float*)d_out;

  const int B  = in_sizes[3] - 1;          // offsets has B+1 entries
  const int NT = 1024 / QT;                // MAX_SEQLEN=1024 -> 32 q-tiles max

  dim3 grid(NT, HH, B);
  dim3 block(256);
  hstu_fp32_kernel<<<grid, block, 0, stream>>>(tq, tk, tv, offsets, pN, ncand,
                                               nctx, out);
}

// Round 2
// 154.860 us; speedup vs baseline: 28.1200x; 28.1200x over previous
//
#include <hip/hip_runtime.h>
#include <math.h>

// HSTU jagged attention, MFMA bf16 version.
// out = (silu(Q K^T) / N * mask) V, no softmax. H=8, D=DV=64, N=1024.
// Mask: a(x)=clamp(x-c+1,0,M), M=L-c+1-ncand;
//   valid(n,m) = (n==m) | (a(n)>a(m)) | (a(n)==0 & a(m)<M), n<L, m<L.
// a nondecreasing => valid implies m<=n (except contextual rows n<c which see all m).

#define HH   8
#define DDIM 64
#define QT   64
#define KT   64

typedef __attribute__((ext_vector_type(8))) short short8;
typedef __attribute__((ext_vector_type(4))) float f32x4;

// fp32 -> bf16 round-to-nearest-even
__device__ __forceinline__ uint f2bf(float f) {
  uint u = __builtin_bit_cast(uint, f);
  u += 0x7FFFu + ((u >> 16) & 1u);
  return u >> 16;
}

__launch_bounds__(256, 4)
__global__ void hstu_mfma_kernel(const float* __restrict__ tq,
                                 const float* __restrict__ tk,
                                 const float* __restrict__ tv,
                                 const int* __restrict__ offsets,
                                 const int* __restrict__ pN,
                                 const int* __restrict__ ncand,
                                 const int* __restrict__ nctx,
                                 float* __restrict__ out) {
  const int b  = blockIdx.z;
  const int h  = blockIdx.y;
  const int qt = blockIdx.x;
  const int off = offsets[b];
  const int L   = offsets[b + 1] - off;
  const int n0  = qt * QT;
  if (n0 >= L) return;

  const float invN = 1.0f / (float)pN[0];
  const int c = nctx[b];
  const int M = L - c + 1 - ncand[b];

  // All tiles bf16, XOR-swizzled in units of 8 halfwords: hw = row*64 + (col ^ ((row&7)<<3))
  __shared__ ushort Qs[QT * DDIM];      // Q[row=q][col=d]      8 KB
  __shared__ ushort Ks[KT * DDIM];      // K[row=k][col=d]      8 KB
  __shared__ ushort Vt[DDIM * KT];      // V^T[row=dv][col=m]   8 KB
  __shared__ ushort Ps[4][16 * KT];     // per-wave P[ql][m]    8 KB

  const int tid  = threadIdx.x;
  const int w    = tid >> 6;
  const int lane = tid & 63;
  const int lo   = lane & 15;
  const int hi   = lane >> 4;

  // ---- stage Q tile once (fp32 -> bf16, swizzled) ----
#pragma unroll
  for (int jj = 0; jj < 4; ++jj) {
    int idx = tid + jj * 256;       // 0..1023 -> 64 rows x 16 float4
    int row = idx >> 4;
    int col = (idx & 15) * 4;
    float4 v = make_float4(0.f, 0.f, 0.f, 0.f);
    int n = n0 + row;
    if (n < L) v = *(const float4*)(tq + (size_t)(off + n) * (HH * DDIM) + h * DDIM + col);
    uint2 pk;
    pk.x = f2bf(v.x) | (f2bf(v.y) << 16);
    pk.y = f2bf(v.z) | (f2bf(v.w) << 16);
    *(uint2*)&Qs[row * 64 + (col ^ ((row & 7) << 3))] = pk;
  }
  __syncthreads();

  // Hoist Q A-frags into registers: q row = w*16+lo, d = ks*32 + hi*8 + [0..7]
  short8 qf[2];
  {
    int qrow = w * 16 + lo;
#pragma unroll
    for (int ks = 0; ks < 2; ++ks)
      qf[ks] = *(const short8*)&Qs[qrow * 64 + ((ks * 32 + hi * 8) ^ ((qrow & 7) << 3))];
  }

  f32x4 oacc[4];
#pragma unroll
  for (int i = 0; i < 4; ++i) oacc[i] = (f32x4){0.f, 0.f, 0.f, 0.f};

  // valid => m<=n except contextual rows (n<c), which live in qt==0 only
  const int m_hi = (n0 < c) ? L : min(n0 + QT, L);

  for (int m0 = 0; m0 < m_hi; m0 += KT) {
    __syncthreads();  // prev tile's readers done before overwrite

    // ---- stage K (row-major bf16, swizzled) ----
#pragma unroll
    for (int jj = 0; jj < 4; ++jj) {
      int idx = tid + jj * 256;
      int row = idx >> 4;
      int col = (idx & 15) * 4;
      float4 v = make_float4(0.f, 0.f, 0.f, 0.f);
      int m = m0 + row;
      if (m < L) v = *(const float4*)(tk + (size_t)(off + m) * (HH * DDIM) + h * DDIM + col);
      uint2 pk;
      pk.x = f2bf(v.x) | (f2bf(v.y) << 16);
      pk.y = f2bf(v.z) | (f2bf(v.w) << 16);
      *(uint2*)&Ks[row * 64 + (col ^ ((row & 7) << 3))] = pk;
    }

    // ---- stage V transposed: Vt[dv][m], loaded column-wise (coalesced 256B) ----
    {
      int dv = lane;
      int mg = w * 8;
#pragma unroll
      for (int half = 0; half < 2; ++half) {
        int ms = half * 32 + mg;
        uint bb[8];
#pragma unroll
        for (int j = 0; j < 8; ++j) {
          float f = 0.f;
          int m = m0 + ms + j;
          if (m < L) f = tv[(size_t)(off + m) * (HH * DDIM) + h * DDIM + dv];
          bb[j] = f2bf(f);
        }
        uint4 pv;
        pv.x = bb[0] | (bb[1] << 16);
        pv.y = bb[2] | (bb[3] << 16);
        pv.z = bb[4] | (bb[5] << 16);
        pv.w = bb[6] | (bb[7] << 16);
        *(uint4*)&Vt[dv * 64 + (ms ^ ((dv & 7) << 3))] = pv;
      }
    }
    __syncthreads();

    // ---- S = Q K^T : wave computes 16 q-rows x 64 k-cols (8 MFMA) ----
    f32x4 sacc[4];
#pragma unroll
    for (int i = 0; i < 4; ++i) sacc[i] = (f32x4){0.f, 0.f, 0.f, 0.f};
#pragma unroll
    for (int kc = 0; kc < 4; ++kc) {
      int krow = kc * 16 + lo;
#pragma unroll
      for (int ks = 0; ks < 2; ++ks) {
        short8 kf = *(const short8*)&Ks[krow * 64 + ((ks * 32 + hi * 8) ^ ((krow & 7) << 3))];
        sacc[kc] = __builtin_amdgcn_mfma_f32_16x16x32_bf16(qf[ks], kf, sacc[kc], 0, 0, 0);
      }
    }

    // ---- mask + silu/N on C-frag (row=4*hi+r, col=lo), write bf16 P to own wave's LDS strip ----
#pragma unroll
    for (int kc = 0; kc < 4; ++kc) {
#pragma unroll
      for (int r = 0; r < 4; ++r) {
        int ql = hi * 4 + r;
        int n  = n0 + w * 16 + ql;
        int mm = m0 + kc * 16 + lo;
        float p = 0.f;
        if (n < L && mm < L) {
          int an = min(max(n - c + 1, 0), M);
          int am = min(max(mm - c + 1, 0), M);
          if ((n == mm) || (an > am) || ((an == 0) && (am < M))) {
            float s = sacc[kc][r];
            p = s * invN / (1.f + __expf(-s));
          }
        }
        int col = kc * 16 + lo;
        Ps[w][ql * 64 + (col ^ ((ql & 7) << 3))] = (ushort)f2bf(p);
      }
    }

    // ---- O += P V : 8 MFMA ----
#pragma unroll
    for (int mc = 0; mc < 2; ++mc) {
      short8 pf = *(const short8*)&Ps[w][lo * 64 + ((mc * 32 + hi * 8) ^ ((lo & 7) << 3))];
#pragma unroll
      for (int dvc = 0; dvc < 4; ++dvc) {
        int vrow = dvc * 16 + lo;
        short8 vf = *(const short8*)&Vt[vrow * 64 + ((mc * 32 + hi * 8) ^ ((vrow & 7) << 3))];
        oacc[dvc] = __builtin_amdgcn_mfma_f32_16x16x32_bf16(pf, vf, oacc[dvc], 0, 0, 0);
      }
    }
  }

  // ---- write out (fp32), C-frag layout ----
#pragma unroll
  for (int dvc = 0; dvc < 4; ++dvc) {
#pragma unroll
    for (int r = 0; r < 4; ++r) {
      int n = n0 + w * 16 + hi * 4 + r;
      if (n < L)
        out[(size_t)(off + n) * (HH * DDIM) + h * DDIM + dvc * 16 + lo] = oacc[dvc][r];
    }
  }
}

extern "C" void kernel_launch(void* const* d_in, const int* in_sizes, int n_in,
                              void* d_out, int out_size, void* d_ws, size_t ws_size,
                              hipStream_t stream) {
  const float* tq      = (const float*)d_in[0];
  const float* tk      = (const float*)d_in[1];
  const float* tv      = (const float*)d_in[2];
  const int*   offsets = (const int*)d_in[3];
  const int*   pN      = (const int*)d_in[4];
  const int*   ncand   = (const int*)d_in[5];
  const int*   nctx    = (const int*)d_in[6];
  float*       out     = (float*)d_out;

  const int B  = in_sizes[3] - 1;
  const int NT = 1024 / QT;   // 16 q-tiles max (MAX_SEQLEN=1024)

  dim3 grid(NT, HH, B);
  dim3 block(256);
  hstu_mfma_kernel<<<grid, block, 0, stream>>>(tq, tk, tv, offsets, pN, ncand,
                                               nctx, out);
}

// Round 3
// 151.985 us; speedup vs baseline: 28.6519x; 1.0189x over previous
//
#include <hip/hip_runtime.h>
#include <math.h>

// HSTU jagged attention, MFMA bf16, reg-staged prefetch pipeline.
// out = (silu(Q K^T) / N * mask) V, no softmax. H=8, D=DV=64, N=1024.
// Mask: a(x)=clamp(x-c+1,0,M), M=L-c+1-ncand;
//   valid(n,m) = (n==m) | (a(n)>a(m)) | (a(n)==0 & a(m)<M), n<L, m<L.
// valid => m<=n except contextual rows n<c (qt==0 sweeps full L).

#define HH     8
#define DDIM   64
#define QT     64
#define KT     64
#define STRIDE (HH * DDIM)   // 512 floats per token row

typedef __attribute__((ext_vector_type(8))) short short8;
typedef __attribute__((ext_vector_type(4))) float f32x4;

__device__ __forceinline__ uint f2bf(float f) {
  uint u = __builtin_bit_cast(uint, f);
  u += 0x7FFFu + ((u >> 16) & 1u);
  return u >> 16;
}

__launch_bounds__(256, 4)
__global__ void hstu_mfma2(const float* __restrict__ tq,
                           const float* __restrict__ tk,
                           const float* __restrict__ tv,
                           const int* __restrict__ offsets,
                           const int* __restrict__ pN,
                           const int* __restrict__ ncand,
                           const int* __restrict__ nctx,
                           float* __restrict__ out, int Tm1) {
  const int b  = blockIdx.z;
  const int h  = blockIdx.y;
  const int bx = blockIdx.x;
  // heavy-first dispatch: qt=0 (full-L contextual sweep) first, then 15,14,...
  const int qt = (bx == 0) ? 0 : ((int)gridDim.x - bx);
  const int off = offsets[b];
  const int L   = offsets[b + 1] - off;
  const int n0  = qt * QT;
  if (n0 >= L) return;

  const float invN = 1.0f / (float)pN[0];
  const int c = nctx[b];
  const int M = L - c + 1 - ncand[b];

  // 24 KB LDS: Q is consumed into registers once, then its space holds P strips.
  __shared__ ushort Ks[KT * DDIM];     // K[k][d], swizzled       8 KB
  __shared__ ushort Vt[DDIM * KT];     // V^T[dv][m], swizzled    8 KB
  __shared__ ushort QPs[QT * DDIM];    // Q[q][d] -> P strips     8 KB

  const int tid  = threadIdx.x;
  const int w    = tid >> 6;
  const int lane = tid & 63;
  const int lo   = lane & 15;
  const int hi   = lane >> 4;

  // load roles
  const int krow = tid >> 4;          // + jj*16 -> K/Q tile row
  const int kcol = (tid & 15) * 4;    // float col

  // ---- issue tile-0 K/V loads immediately (latency hides under Q staging) ----
  float4 kreg[4];
  float  vreg[16];
#pragma unroll
  for (int jj = 0; jj < 4; ++jj) {
    int r = min(off + krow + jj * 16, Tm1);
    kreg[jj] = *(const float4*)(tk + (size_t)r * STRIDE + h * DDIM + kcol);
  }
#pragma unroll
  for (int j = 0; j < 16; ++j) {
    int r = min(off + w * 16 + j, Tm1);
    vreg[j] = tv[(size_t)r * STRIDE + h * DDIM + lane];
  }

  // ---- stage Q (fp32 -> bf16, swizzled), hoist A-frags, then free the LDS ----
#pragma unroll
  for (int jj = 0; jj < 4; ++jj) {
    int row = krow + jj * 16;
    int r   = min(off + n0 + row, Tm1);
    float4 v = *(const float4*)(tq + (size_t)r * STRIDE + h * DDIM + kcol);
    uint2 pk;
    pk.x = f2bf(v.x) | (f2bf(v.y) << 16);
    pk.y = f2bf(v.z) | (f2bf(v.w) << 16);
    *(uint2*)&QPs[row * 64 + (kcol ^ ((row & 7) << 3))] = pk;
  }
  __syncthreads();
  short8 qf[2];
  {
    int qrow = w * 16 + lo;
#pragma unroll
    for (int ks = 0; ks < 2; ++ks)
      qf[ks] = *(const short8*)&QPs[qrow * 64 + ((ks * 32 + hi * 8) ^ ((qrow & 7) << 3))];
  }

  // n-side mask terms (iteration-invariant)
  int  n_r[4], an_r[4];
  bool nok[4], anz[4];
#pragma unroll
  for (int r = 0; r < 4; ++r) {
    n_r[r]  = n0 + w * 16 + hi * 4 + r;
    an_r[r] = min(max(n_r[r] - c + 1, 0), M);
    nok[r]  = n_r[r] < L;
    anz[r]  = (an_r[r] == 0);
  }

  f32x4 oacc[4];
#pragma unroll
  for (int i = 0; i < 4; ++i) oacc[i] = (f32x4){0.f, 0.f, 0.f, 0.f};

  const int m_hi  = (n0 < c) ? L : min(n0 + QT, L);
  const int niter = (m_hi + KT - 1) / KT;
  ushort* Pw = &QPs[w * 1024];

  for (int t = 0; t < niter; ++t) {
    const int m0 = t * KT;
    __syncthreads();  // prior iter's LDS readers done (t=0: Q-frag hoist drained)

    // ---- convert + ds_write current tile (vmcnt wait is implicit on reg use) ----
#pragma unroll
    for (int jj = 0; jj < 4; ++jj) {
      int row = krow + jj * 16;
      uint2 pk;
      pk.x = f2bf(kreg[jj].x) | (f2bf(kreg[jj].y) << 16);
      pk.y = f2bf(kreg[jj].z) | (f2bf(kreg[jj].w) << 16);
      *(uint2*)&Ks[row * 64 + (kcol ^ ((row & 7) << 3))] = pk;
    }
    {
      uint bb[16];
#pragma unroll
      for (int j = 0; j < 16; ++j) bb[j] = f2bf(vreg[j]);
      uint4 p0, p1;
      p0.x = bb[0] | (bb[1] << 16);  p0.y = bb[2]  | (bb[3] << 16);
      p0.z = bb[4] | (bb[5] << 16);  p0.w = bb[6]  | (bb[7] << 16);
      p1.x = bb[8] | (bb[9] << 16);  p1.y = bb[10] | (bb[11] << 16);
      p1.z = bb[12]| (bb[13] << 16); p1.w = bb[14] | (bb[15] << 16);
      int s = (lane & 7) << 3;
      *(uint4*)&Vt[lane * 64 + ((w * 16)     ^ s)] = p0;
      *(uint4*)&Vt[lane * 64 + ((w * 16 + 8) ^ s)] = p1;
    }

    // ---- issue next tile's loads (consumed next iteration -> latency hidden) ----
    if (t + 1 < niter) {
      const int mn = (t + 1) * KT;
#pragma unroll
      for (int jj = 0; jj < 4; ++jj) {
        int r = min(off + mn + krow + jj * 16, Tm1);
        kreg[jj] = *(const float4*)(tk + (size_t)r * STRIDE + h * DDIM + kcol);
      }
#pragma unroll
      for (int j = 0; j < 16; ++j) {
        int r = min(off + mn + w * 16 + j, Tm1);
        vreg[j] = tv[(size_t)r * STRIDE + h * DDIM + lane];
      }
    }
    __syncthreads();  // K/V tile visible

    // ---- S = Q K^T (8 MFMA) ----
    f32x4 sacc[4];
#pragma unroll
    for (int i = 0; i < 4; ++i) sacc[i] = (f32x4){0.f, 0.f, 0.f, 0.f};
#pragma unroll
    for (int kc = 0; kc < 4; ++kc) {
      int krw = kc * 16 + lo;
#pragma unroll
      for (int ks = 0; ks < 2; ++ks) {
        short8 kf = *(const short8*)&Ks[krw * 64 + ((ks * 32 + hi * 8) ^ ((krw & 7) << 3))];
        sacc[kc] = __builtin_amdgcn_mfma_f32_16x16x32_bf16(qf[ks], kf, sacc[kc], 0, 0, 0);
      }
    }

    // ---- mask + silu/N, P -> own wave's LDS strip (branchless, no NaN) ----
#pragma unroll
    for (int kc = 0; kc < 4; ++kc) {
      int mm = m0 + kc * 16 + lo;
      int am = min(max(mm - c + 1, 0), M);
      bool mok   = mm < L;
      bool amltM = am < M;
#pragma unroll
      for (int r = 0; r < 4; ++r) {
        bool valid = nok[r] & mok &
                     ((n_r[r] == mm) | (an_r[r] > am) | (anz[r] & amltM));
        float s = valid ? sacc[kc][r] : 0.f;   // silu(0)=0
        float p = s * invN * __builtin_amdgcn_rcpf(1.f + __expf(-s));
        int col = kc * 16 + lo;
        int ql  = hi * 4 + r;
        Pw[ql * 64 + (col ^ ((ql & 7) << 3))] = (ushort)f2bf(p);
      }
    }

    // ---- O += P V (8 MFMA); P round-trip is wave-private (no barrier) ----
#pragma unroll
    for (int mc = 0; mc < 2; ++mc) {
      short8 pf = *(const short8*)&Pw[lo * 64 + ((mc * 32 + hi * 8) ^ ((lo & 7) << 3))];
#pragma unroll
      for (int dvc = 0; dvc < 4; ++dvc) {
        int vrow = dvc * 16 + lo;
        short8 vf = *(const short8*)&Vt[vrow * 64 + ((mc * 32 + hi * 8) ^ ((vrow & 7) << 3))];
        oacc[dvc] = __builtin_amdgcn_mfma_f32_16x16x32_bf16(pf, vf, oacc[dvc], 0, 0, 0);
      }
    }
  }

  // ---- write out (fp32), C-frag layout ----
#pragma unroll
  for (int dvc = 0; dvc < 4; ++dvc) {
#pragma unroll
    for (int r = 0; r < 4; ++r) {
      int n = n0 + w * 16 + hi * 4 + r;
      if (n < L)
        out[(size_t)(off + n) * STRIDE + h * DDIM + dvc * 16 + lo] = oacc[dvc][r];
    }
  }
}

extern "C" void kernel_launch(void* const* d_in, const int* in_sizes, int n_in,
                              void* d_out, int out_size, void* d_ws, size_t ws_size,
                              hipStream_t stream) {
  const float* tq      = (const float*)d_in[0];
  const float* tk      = (const float*)d_in[1];
  const float* tv      = (const float*)d_in[2];
  const int*   offsets = (const int*)d_in[3];
  const int*   pN      = (const int*)d_in[4];
  const int*   ncand   = (const int*)d_in[5];
  const int*   nctx    = (const int*)d_in[6];
  float*       out     = (float*)d_out;

  const int B   = in_sizes[3] - 1;
  const int T   = in_sizes[0] / STRIDE;
  const int NT  = 1024 / QT;   // MAX_SEQLEN=1024 -> 16 q-tiles

  dim3 grid(NT, HH, B);
  dim3 block(256);
  hstu_mfma2<<<grid, block, 0, stream>>>(tq, tk, tv, offsets, pN, ncand, nctx,
                                         out, T - 1);
}

// Round 4
// 149.137 us; speedup vs baseline: 29.1991x; 1.0191x over previous
//
#include <hip/hip_runtime.h>
#include <math.h>

// HSTU jagged attention, MFMA bf16, trapezoid-paired q-tiles for load balance.
// out = (silu(Q K^T) / N * mask) V, no softmax. H=8, D=DV=64, N=1024.
// Mask: a(x)=clamp(x-c+1,0,M), M=L-c+1-ncand;
//   valid(n,m) = (n==m) | (a(n)>a(m)) | (a(n)==0 & a(m)<M), n<L, m<L.
// valid => m<=n except contextual rows n<c (qt==0 sweeps full L).
// Block p: p==0 -> {qt=0}; p>=1 -> {p, nq-p} (dedup'd) => ~uniform nq+2 iters.

#define HH     8
#define DDIM   64
#define QT     64
#define KT     64
#define STRIDE (HH * DDIM)   // 512 floats per token row

typedef __attribute__((ext_vector_type(8))) short short8;
typedef __attribute__((ext_vector_type(4))) float f32x4;

__device__ __forceinline__ uint f2bf(float f) {
  uint u = __builtin_bit_cast(uint, f);
  u += 0x7FFFu + ((u >> 16) & 1u);
  return u >> 16;
}

__launch_bounds__(256, 4)
__global__ void hstu_mfma3(const float* __restrict__ tq,
                           const float* __restrict__ tk,
                           const float* __restrict__ tv,
                           const int* __restrict__ offsets,
                           const int* __restrict__ pN,
                           const int* __restrict__ ncand,
                           const int* __restrict__ nctx,
                           float* __restrict__ out, int Tm1) {
  const int b  = blockIdx.z;
  const int h  = blockIdx.y;
  const int p  = blockIdx.x;            // 0..8
  const int off = offsets[b];
  const int L   = offsets[b + 1] - off;
  const int nq  = (L + QT - 1) / QT;    // q-tiles in this batch

  // trapezoid pairing: uniform work per block
  int qlist[2];
  int nph = 0;
  if (p == 0) {
    qlist[nph++] = 0;
  } else {
    int qa = p, qb = nq - p;
    if (qa < nq && qa <= qb) qlist[nph++] = qa;
    if (qb < nq && qb > qa)  qlist[nph++] = qb;
  }
  if (nph == 0) return;

  const float invN = 1.0f / (float)pN[0];
  const int c = nctx[b];
  const int M = L - c + 1 - ncand[b];

  // 24 KB LDS: Q is consumed into registers, then its space holds P strips.
  __shared__ ushort Ks[KT * DDIM];     // K[k][d], swizzled       8 KB
  __shared__ ushort Vt[DDIM * KT];     // V^T[dv][m], swizzled    8 KB
  __shared__ ushort QPs[QT * DDIM];    // Q[q][d] -> P strips     8 KB

  const int tid  = threadIdx.x;
  const int w    = tid >> 6;
  const int lane = tid & 63;
  const int lo   = lane & 15;
  const int hi   = lane >> 4;

  const int krow = tid >> 4;          // + jj*16 -> K/Q tile row
  const int kcol = (tid & 15) * 4;    // float col

  float4 kreg[4];
  float  vreg[16];
  ushort* Pw = &QPs[w * 1024];

  for (int ph = 0; ph < nph; ++ph) {
    const int qt = qlist[ph];
    const int n0 = qt * QT;

    __syncthreads();  // prior phase's LDS readers (P/V/K) done before restage

    // ---- issue this phase's tile-0 K/V loads (latency hides under Q staging) ----
#pragma unroll
    for (int jj = 0; jj < 4; ++jj) {
      int r = min(off + krow + jj * 16, Tm1);
      kreg[jj] = *(const float4*)(tk + (size_t)r * STRIDE + h * DDIM + kcol);
    }
#pragma unroll
    for (int j = 0; j < 16; ++j) {
      int r = min(off + w * 16 + j, Tm1);
      vreg[j] = tv[(size_t)r * STRIDE + h * DDIM + lane];
    }

    // ---- stage Q (fp32 -> bf16, swizzled), hoist A-frags ----
#pragma unroll
    for (int jj = 0; jj < 4; ++jj) {
      int row = krow + jj * 16;
      int r   = min(off + n0 + row, Tm1);
      float4 v = *(const float4*)(tq + (size_t)r * STRIDE + h * DDIM + kcol);
      uint2 pk;
      pk.x = f2bf(v.x) | (f2bf(v.y) << 16);
      pk.y = f2bf(v.z) | (f2bf(v.w) << 16);
      *(uint2*)&QPs[row * 64 + (kcol ^ ((row & 7) << 3))] = pk;
    }
    __syncthreads();
    short8 qf[2];
    {
      int qrow = w * 16 + lo;
#pragma unroll
      for (int ks = 0; ks < 2; ++ks)
        qf[ks] = *(const short8*)&QPs[qrow * 64 + ((ks * 32 + hi * 8) ^ ((qrow & 7) << 3))];
    }

    // n-side mask terms (iteration-invariant)
    int  n_r[4], an_r[4];
    bool nok[4], anz[4];
#pragma unroll
    for (int r = 0; r < 4; ++r) {
      n_r[r]  = n0 + w * 16 + hi * 4 + r;
      an_r[r] = min(max(n_r[r] - c + 1, 0), M);
      nok[r]  = n_r[r] < L;
      anz[r]  = (an_r[r] == 0);
    }

    f32x4 oacc[4];
#pragma unroll
    for (int i = 0; i < 4; ++i) oacc[i] = (f32x4){0.f, 0.f, 0.f, 0.f};

    const int m_hi  = (n0 < c) ? L : min(n0 + QT, L);
    const int niter = (m_hi + KT - 1) / KT;

    for (int t = 0; t < niter; ++t) {
      const int m0 = t * KT;
      __syncthreads();  // prior iter's LDS readers done (t=0: Q-frag hoist drained)

      // ---- convert + ds_write current K/V tile ----
#pragma unroll
      for (int jj = 0; jj < 4; ++jj) {
        int row = krow + jj * 16;
        uint2 pk;
        pk.x = f2bf(kreg[jj].x) | (f2bf(kreg[jj].y) << 16);
        pk.y = f2bf(kreg[jj].z) | (f2bf(kreg[jj].w) << 16);
        *(uint2*)&Ks[row * 64 + (kcol ^ ((row & 7) << 3))] = pk;
      }
      {
        uint bb[16];
#pragma unroll
        for (int j = 0; j < 16; ++j) bb[j] = f2bf(vreg[j]);
        uint4 p0, p1;
        p0.x = bb[0] | (bb[1] << 16);  p0.y = bb[2]  | (bb[3] << 16);
        p0.z = bb[4] | (bb[5] << 16);  p0.w = bb[6]  | (bb[7] << 16);
        p1.x = bb[8] | (bb[9] << 16);  p1.y = bb[10] | (bb[11] << 16);
        p1.z = bb[12]| (bb[13] << 16); p1.w = bb[14] | (bb[15] << 16);
        int s = (lane & 7) << 3;
        *(uint4*)&Vt[lane * 64 + ((w * 16)     ^ s)] = p0;
        *(uint4*)&Vt[lane * 64 + ((w * 16 + 8) ^ s)] = p1;
      }

      // ---- issue next tile's loads (consumed next iteration) ----
      if (t + 1 < niter) {
        const int mn = (t + 1) * KT;
#pragma unroll
        for (int jj = 0; jj < 4; ++jj) {
          int r = min(off + mn + krow + jj * 16, Tm1);
          kreg[jj] = *(const float4*)(tk + (size_t)r * STRIDE + h * DDIM + kcol);
        }
#pragma unroll
        for (int j = 0; j < 16; ++j) {
          int r = min(off + mn + w * 16 + j, Tm1);
          vreg[j] = tv[(size_t)r * STRIDE + h * DDIM + lane];
        }
      }
      __syncthreads();  // K/V tile visible

      // ---- S = Q K^T (8 MFMA) ----
      f32x4 sacc[4];
#pragma unroll
      for (int i = 0; i < 4; ++i) sacc[i] = (f32x4){0.f, 0.f, 0.f, 0.f};
#pragma unroll
      for (int kc = 0; kc < 4; ++kc) {
        int krw = kc * 16 + lo;
#pragma unroll
        for (int ks = 0; ks < 2; ++ks) {
          short8 kf = *(const short8*)&Ks[krw * 64 + ((ks * 32 + hi * 8) ^ ((krw & 7) << 3))];
          sacc[kc] = __builtin_amdgcn_mfma_f32_16x16x32_bf16(qf[ks], kf, sacc[kc], 0, 0, 0);
        }
      }

      // ---- mask + silu/N, P -> own wave's LDS strip (branchless, no NaN) ----
#pragma unroll
      for (int kc = 0; kc < 4; ++kc) {
        int mm = m0 + kc * 16 + lo;
        int am = min(max(mm - c + 1, 0), M);
        bool mok   = mm < L;
        bool amltM = am < M;
#pragma unroll
        for (int r = 0; r < 4; ++r) {
          bool valid = nok[r] & mok &
                       ((n_r[r] == mm) | (an_r[r] > am) | (anz[r] & amltM));
          float s = valid ? sacc[kc][r] : 0.f;   // silu(0)=0
          float pp = s * invN * __builtin_amdgcn_rcpf(1.f + __expf(-s));
          int col = kc * 16 + lo;
          int ql  = hi * 4 + r;
          Pw[ql * 64 + (col ^ ((ql & 7) << 3))] = (ushort)f2bf(pp);
        }
      }

      // ---- O += P V (8 MFMA); P round-trip is wave-private (no barrier) ----
#pragma unroll
      for (int mc = 0; mc < 2; ++mc) {
        short8 pf = *(const short8*)&Pw[lo * 64 + ((mc * 32 + hi * 8) ^ ((lo & 7) << 3))];
#pragma unroll
        for (int dvc = 0; dvc < 4; ++dvc) {
          int vrow = dvc * 16 + lo;
          short8 vf = *(const short8*)&Vt[vrow * 64 + ((mc * 32 + hi * 8) ^ ((vrow & 7) << 3))];
          oacc[dvc] = __builtin_amdgcn_mfma_f32_16x16x32_bf16(pf, vf, oacc[dvc], 0, 0, 0);
        }
      }
    }

    // ---- write out (fp32), C-frag layout ----
#pragma unroll
    for (int dvc = 0; dvc < 4; ++dvc) {
#pragma unroll
      for (int r = 0; r < 4; ++r) {
        int n = n0 + w * 16 + hi * 4 + r;
        if (n < L)
          out[(size_t)(off + n) * STRIDE + h * DDIM + dvc * 16 + lo] = oacc[dvc][r];
      }
    }
  }
}

extern "C" void kernel_launch(void* const* d_in, const int* in_sizes, int n_in,
                              void* d_out, int out_size, void* d_ws, size_t ws_size,
                              hipStream_t stream) {
  const float* tq      = (const float*)d_in[0];
  const float* tk      = (const float*)d_in[1];
  const float* tv      = (const float*)d_in[2];
  const int*   offsets = (const int*)d_in[3];
  const int*   pN      = (const int*)d_in[4];
  const int*   ncand   = (const int*)d_in[5];
  const int*   nctx    = (const int*)d_in[6];
  float*       out     = (float*)d_out;

  const int B  = in_sizes[3] - 1;
  const int T  = in_sizes[0] / STRIDE;
  const int NP = 9;   // pairs: p=0 (contextual) + p=1..8 covering {p, nq-p}

  dim3 grid(NP, HH, B);
  dim3 block(256);
  hstu_mfma3<<<grid, block, 0, stream>>>(tq, tk, tv, offsets, pN, ncand, nctx,
                                         out, T - 1);
}

// Round 5
// 107.800 us; speedup vs baseline: 40.3956x; 1.3835x over previous
//
#include <hip/hip_runtime.h>
#include <math.h>

// HSTU jagged attention, MFMA bf16.
// R5: pre-convert K/V to bf16 in d_ws (kills inner-loop f2bf + register spills),
//     relaxed launch bounds. Trapezoid-paired q-tiles (uniform work/block).
// out = (silu(Q K^T) / N * mask) V, no softmax. H=8, D=DV=64, N=1024.
// Mask: a(x)=clamp(x-c+1,0,M), M=L-c+1-ncand;
//   valid(n,m) = (n==m) | (a(n)>a(m)) | (a(n)==0 & a(m)<M), n<L, m<L.

#define HH     8
#define DDIM   64
#define QT     64
#define KT     64
#define STRIDE (HH * DDIM)   // 512 elems per token row

typedef __attribute__((ext_vector_type(8))) short short8;
typedef __attribute__((ext_vector_type(4))) float f32x4;

__device__ __forceinline__ uint f2bf(float f) {
  uint u = __builtin_bit_cast(uint, f);
  u += 0x7FFFu + ((u >> 16) & 1u);
  return u >> 16;
}

// ---- pre-pass: fp32 -> bf16 (RNE), 8 elems/thread, grid-stride ----
__global__ void conv_bf16_kernel(const float* __restrict__ in,
                                 ushort* __restrict__ out, int n8) {
  int i = blockIdx.x * blockDim.x + threadIdx.x;
  const int gs = gridDim.x * blockDim.x;
  for (; i < n8; i += gs) {
    const float4* p = (const float4*)(in + (size_t)i * 8);
    float4 a = p[0], b = p[1];
    uint4 o;
    o.x = f2bf(a.x) | (f2bf(a.y) << 16);
    o.y = f2bf(a.z) | (f2bf(a.w) << 16);
    o.z = f2bf(b.x) | (f2bf(b.y) << 16);
    o.w = f2bf(b.z) | (f2bf(b.w) << 16);
    *(uint4*)(out + (size_t)i * 8) = o;
  }
}

template <bool PRE>
__launch_bounds__(256)
__global__ void hstu_mfma4(const float* __restrict__ tq,
                           const float* __restrict__ tk,
                           const float* __restrict__ tv,
                           const ushort* __restrict__ kbf,
                           const ushort* __restrict__ vbf,
                           const int* __restrict__ offsets,
                           const int* __restrict__ pN,
                           const int* __restrict__ ncand,
                           const int* __restrict__ nctx,
                           float* __restrict__ out, int Tm1) {
  const int b  = blockIdx.z;
  const int h  = blockIdx.y;
  const int p  = blockIdx.x;            // 0..8
  const int off = offsets[b];
  const int L   = offsets[b + 1] - off;
  const int nq  = (L + QT - 1) / QT;

  // trapezoid pairing: ~uniform nq+2 iterations per block
  int q0 = -1, q1 = -1;
  if (p == 0) {
    q0 = 0;
  } else {
    int qa = p, qb = nq - p;
    if (qa < nq && qa <= qb) { q0 = qa; if (qb < nq && qb > qa) q1 = qb; }
    else if (qb > 0 && qb < nq) q0 = qb;
  }
  if (q0 < 0) return;
  const int nph = (q1 >= 0) ? 2 : 1;

  const float invN = 1.0f / (float)pN[0];
  const int c = nctx[b];
  const int M = L - c + 1 - ncand[b];

  __shared__ ushort Ks[KT * DDIM];     // K[k][d], swizzled       8 KB
  __shared__ ushort Vt[DDIM * KT];     // V^T[dv][m], swizzled    8 KB
  __shared__ ushort QPs[QT * DDIM];    // Q[q][d] then P strips   8 KB

  const int tid  = threadIdx.x;
  const int w    = tid >> 6;
  const int lane = tid & 63;
  const int lo   = lane & 15;
  const int hi   = lane >> 4;

  // staging roles
  const int qrow4 = tid >> 4;          // Q: 16 threads/row, float4
  const int qcol4 = (tid & 15) * 4;
  const int k_r   = tid >> 3;          // K(bf16): 8 threads/row, uint4=8hw
  const int k_c   = (tid & 7) * 8;     // halfword col

  // prefetch registers
  uint4  kpre[2];          // PRE: rows k_r, k_r+32 (8 VGPR)
  uint   vpre[8];          // PRE: col=lane, rows w*16+2j,2j+1 packed (8 VGPR)
  float4 kpf[4];           // fallback
  float  vpf[16];          // fallback

  ushort* Pw = &QPs[w * 1024];

  for (int ph = 0; ph < nph; ++ph) {
    const int qt = (ph == 0) ? q0 : q1;
    const int n0 = qt * QT;

    __syncthreads();  // prior phase's LDS readers done before restage

    // ---- issue tile-0 K/V loads (latency hides under Q staging) ----
    if (PRE) {
#pragma unroll
      for (int i = 0; i < 2; ++i) {
        int r = min(off + k_r + i * 32, Tm1);
        kpre[i] = *(const uint4*)(kbf + (size_t)r * STRIDE + h * DDIM + k_c);
      }
#pragma unroll
      for (int j = 0; j < 8; ++j) {
        int ra = min(off + w * 16 + 2 * j,     Tm1);
        int rb = min(off + w * 16 + 2 * j + 1, Tm1);
        uint a = vbf[(size_t)ra * STRIDE + h * DDIM + lane];
        uint bb = vbf[(size_t)rb * STRIDE + h * DDIM + lane];
        vpre[j] = a | (bb << 16);
      }
    } else {
#pragma unroll
      for (int jj = 0; jj < 4; ++jj) {
        int r = min(off + qrow4 + jj * 16, Tm1);
        kpf[jj] = *(const float4*)(tk + (size_t)r * STRIDE + h * DDIM + qcol4);
      }
#pragma unroll
      for (int j = 0; j < 16; ++j) {
        int r = min(off + w * 16 + j, Tm1);
        vpf[j] = tv[(size_t)r * STRIDE + h * DDIM + lane];
      }
    }

    // ---- stage Q (fp32 -> bf16, swizzled), hoist A-frags ----
#pragma unroll
    for (int jj = 0; jj < 4; ++jj) {
      int row = qrow4 + jj * 16;
      int r   = min(off + n0 + row, Tm1);
      float4 v = *(const float4*)(tq + (size_t)r * STRIDE + h * DDIM + qcol4);
      uint2 pk;
      pk.x = f2bf(v.x) | (f2bf(v.y) << 16);
      pk.y = f2bf(v.z) | (f2bf(v.w) << 16);
      *(uint2*)&QPs[row * 64 + (qcol4 ^ ((row & 7) << 3))] = pk;
    }
    __syncthreads();
    short8 qf[2];
    {
      int qrow = w * 16 + lo;
#pragma unroll
      for (int ks = 0; ks < 2; ++ks)
        qf[ks] = *(const short8*)&QPs[qrow * 64 + ((ks * 32 + hi * 8) ^ ((qrow & 7) << 3))];
    }

    // n-side mask terms (iteration-invariant)
    int  n_r[4], an_r[4];
    bool nok[4], anz[4];
#pragma unroll
    for (int r = 0; r < 4; ++r) {
      n_r[r]  = n0 + w * 16 + hi * 4 + r;
      an_r[r] = min(max(n_r[r] - c + 1, 0), M);
      nok[r]  = n_r[r] < L;
      anz[r]  = (an_r[r] == 0);
    }

    f32x4 oacc[4];
#pragma unroll
    for (int i = 0; i < 4; ++i) oacc[i] = (f32x4){0.f, 0.f, 0.f, 0.f};

    const int m_hi  = (n0 < c) ? L : min(n0 + QT, L);
    const int niter = (m_hi + KT - 1) / KT;

    for (int t = 0; t < niter; ++t) {
      const int m0 = t * KT;
      __syncthreads();  // prior iter's LDS readers done (t=0: Q hoist drained)

      // ---- ds_write current K/V tile from prefetch regs ----
      if (PRE) {
#pragma unroll
        for (int i = 0; i < 2; ++i) {
          int row = k_r + i * 32;
          *(uint4*)&Ks[row * 64 + (k_c ^ ((row & 7) << 3))] = kpre[i];
        }
        uint4 p0, p1;
        p0.x = vpre[0]; p0.y = vpre[1]; p0.z = vpre[2]; p0.w = vpre[3];
        p1.x = vpre[4]; p1.y = vpre[5]; p1.z = vpre[6]; p1.w = vpre[7];
        int s = (lane & 7) << 3;
        *(uint4*)&Vt[lane * 64 + ((w * 16)     ^ s)] = p0;
        *(uint4*)&Vt[lane * 64 + ((w * 16 + 8) ^ s)] = p1;
      } else {
#pragma unroll
        for (int jj = 0; jj < 4; ++jj) {
          int row = qrow4 + jj * 16;
          uint2 pk;
          pk.x = f2bf(kpf[jj].x) | (f2bf(kpf[jj].y) << 16);
          pk.y = f2bf(kpf[jj].z) | (f2bf(kpf[jj].w) << 16);
          *(uint2*)&Ks[row * 64 + (qcol4 ^ ((row & 7) << 3))] = pk;
        }
        uint bb[16];
#pragma unroll
        for (int j = 0; j < 16; ++j) bb[j] = f2bf(vpf[j]);
        uint4 p0, p1;
        p0.x = bb[0] | (bb[1] << 16);  p0.y = bb[2]  | (bb[3] << 16);
        p0.z = bb[4] | (bb[5] << 16);  p0.w = bb[6]  | (bb[7] << 16);
        p1.x = bb[8] | (bb[9] << 16);  p1.y = bb[10] | (bb[11] << 16);
        p1.z = bb[12]| (bb[13] << 16); p1.w = bb[14] | (bb[15] << 16);
        int s = (lane & 7) << 3;
        *(uint4*)&Vt[lane * 64 + ((w * 16)     ^ s)] = p0;
        *(uint4*)&Vt[lane * 64 + ((w * 16 + 8) ^ s)] = p1;
      }

      // ---- issue next tile's loads (consumed next iteration) ----
      if (t + 1 < niter) {
        const int mn = m0 + KT;
        if (PRE) {
#pragma unroll
          for (int i = 0; i < 2; ++i) {
            int r = min(off + mn + k_r + i * 32, Tm1);
            kpre[i] = *(const uint4*)(kbf + (size_t)r * STRIDE + h * DDIM + k_c);
          }
#pragma unroll
          for (int j = 0; j < 8; ++j) {
            int ra = min(off + mn + w * 16 + 2 * j,     Tm1);
            int rb = min(off + mn + w * 16 + 2 * j + 1, Tm1);
            uint a = vbf[(size_t)ra * STRIDE + h * DDIM + lane];
            uint bb = vbf[(size_t)rb * STRIDE + h * DDIM + lane];
            vpre[j] = a | (bb << 16);
          }
        } else {
#pragma unroll
          for (int jj = 0; jj < 4; ++jj) {
            int r = min(off + mn + qrow4 + jj * 16, Tm1);
            kpf[jj] = *(const float4*)(tk + (size_t)r * STRIDE + h * DDIM + qcol4);
          }
#pragma unroll
          for (int j = 0; j < 16; ++j) {
            int r = min(off + mn + w * 16 + j, Tm1);
            vpf[j] = tv[(size_t)r * STRIDE + h * DDIM + lane];
          }
        }
      }
      __syncthreads();  // K/V tile visible

      // ---- S = Q K^T (8 MFMA) ----
      f32x4 sacc[4];
#pragma unroll
      for (int i = 0; i < 4; ++i) sacc[i] = (f32x4){0.f, 0.f, 0.f, 0.f};
#pragma unroll
      for (int kc = 0; kc < 4; ++kc) {
        int krw = kc * 16 + lo;
#pragma unroll
        for (int ks = 0; ks < 2; ++ks) {
          short8 kf = *(const short8*)&Ks[krw * 64 + ((ks * 32 + hi * 8) ^ ((krw & 7) << 3))];
          sacc[kc] = __builtin_amdgcn_mfma_f32_16x16x32_bf16(qf[ks], kf, sacc[kc], 0, 0, 0);
        }
      }

      // ---- mask + silu/N, P -> own wave's LDS strip (branchless, no NaN) ----
#pragma unroll
      for (int kc = 0; kc < 4; ++kc) {
        int mm = m0 + kc * 16 + lo;
        int am = min(max(mm - c + 1, 0), M);
        bool mok   = mm < L;
        bool amltM = am < M;
#pragma unroll
        for (int r = 0; r < 4; ++r) {
          bool valid = nok[r] & mok &
                       ((n_r[r] == mm) | (an_r[r] > am) | (anz[r] & amltM));
          float s = valid ? sacc[kc][r] : 0.f;   // silu(0)=0
          float pp = s * invN * __builtin_amdgcn_rcpf(1.f + __expf(-s));
          int col = kc * 16 + lo;
          int ql  = hi * 4 + r;
          Pw[ql * 64 + (col ^ ((ql & 7) << 3))] = (ushort)f2bf(pp);
        }
      }

      // ---- O += P V (8 MFMA); P round-trip is wave-private (no barrier) ----
#pragma unroll
      for (int mc = 0; mc < 2; ++mc) {
        short8 pf = *(const short8*)&Pw[lo * 64 + ((mc * 32 + hi * 8) ^ ((lo & 7) << 3))];
#pragma unroll
        for (int dvc = 0; dvc < 4; ++dvc) {
          int vrow = dvc * 16 + lo;
          short8 vf = *(const short8*)&Vt[vrow * 64 + ((mc * 32 + hi * 8) ^ ((vrow & 7) << 3))];
          oacc[dvc] = __builtin_amdgcn_mfma_f32_16x16x32_bf16(pf, vf, oacc[dvc], 0, 0, 0);
        }
      }
    }

    // ---- write out (fp32), C-frag layout ----
#pragma unroll
    for (int dvc = 0; dvc < 4; ++dvc) {
#pragma unroll
      for (int r = 0; r < 4; ++r) {
        int n = n0 + w * 16 + hi * 4 + r;
        if (n < L)
          out[(size_t)(off + n) * STRIDE + h * DDIM + dvc * 16 + lo] = oacc[dvc][r];
      }
    }
  }
}

extern "C" void kernel_launch(void* const* d_in, const int* in_sizes, int n_in,
                              void* d_out, int out_size, void* d_ws, size_t ws_size,
                              hipStream_t stream) {
  const float* tq      = (const float*)d_in[0];
  const float* tk      = (const float*)d_in[1];
  const float* tv      = (const float*)d_in[2];
  const int*   offsets = (const int*)d_in[3];
  const int*   pN      = (const int*)d_in[4];
  const int*   ncand   = (const int*)d_in[5];
  const int*   nctx    = (const int*)d_in[6];
  float*       out     = (float*)d_out;

  const int B  = in_sizes[3] - 1;
  const int T  = in_sizes[0] / STRIDE;
  const int NP = 9;   // p=0 (contextual) + p=1..8 covering {p, nq-p}

  dim3 grid(NP, HH, B);
  dim3 block(256);

  const size_t need = (size_t)T * STRIDE * sizeof(ushort) * 2;
  if (ws_size >= need) {
    ushort* kbf = (ushort*)d_ws;
    ushort* vbf = kbf + (size_t)T * STRIDE;
    const int n8 = T * STRIDE / 8;
    int nb = (n8 + 255) / 256;
    if (nb > 2048) nb = 2048;
    conv_bf16_kernel<<<nb, 256, 0, stream>>>(tk, kbf, n8);
    conv_bf16_kernel<<<nb, 256, 0, stream>>>(tv, vbf, n8);
    hstu_mfma4<true><<<grid, block, 0, stream>>>(tq, tk, tv, kbf, vbf, offsets,
                                                 pN, ncand, nctx, out, T - 1);
  } else {
    hstu_mfma4<false><<<grid, block, 0, stream>>>(tq, tk, tv, nullptr, nullptr,
                                                  offsets, pN, ncand, nctx, out,
                                                  T - 1);
  }
}